// Round 15
// baseline (9323.248 us; speedup 1.0000x reference)
//
#include <hip/hip_runtime.h>
#include <math.h>

#define B_    32
#define S_    2048
#define DIN   256
#define H_    512
#define G_    2048
#define DOUT  256
#define T_    2048
#define NBLK  200

typedef __attribute__((ext_vector_type(8))) _Float16 f16x8;
typedef __attribute__((ext_vector_type(16))) float f32x16;
typedef __attribute__((ext_vector_type(2))) float f32x2;

#define MFMA(a,b,c) __builtin_amdgcn_mfma_f32_32x32x16_f16((a),(b),(c),0,0,0)

// ---- ws byte offsets ----
#define OB_SLOT      0u          // 200 progress slots (int), 64B stride
#define OB_H0H       16384u      // fp16 FRAGMENT layout [4][32 kw][64 lane][8] ring
#define OB_H1H       147456u
#define OB_PART      278528u     // f32 [4][64][1024] partial-gate ring (1 MB)
#define OB_STATE_END 1327104u
#define OB_B0        1327104u    // fp32 [2048] combined bias (packed cols)
#define OB_B1        1335296u
#define OB_WF        1343488u    // fp16 [256][512]   Wfc^T
#define OB_W0        1605632u    // fp16 [2048][768]  packed-col-major
#define OB_W1        4751360u    // fp16 [2048][1024]
#define OB_END       8945664u
#define OB_XF        8945664u    // fp16 x in fragment layout [S][16 kw][64][8]
#define OB_XEND      42500096u

// ---- dynamic LDS ----
#define LS_PT    49152           // W: [0,49152) ; Pt: float[4][32][32]
#define LS_CST   65536           // float[256]
#define LS_TOTAL 66560

__device__ __forceinline__ float sigf(float v) {
    return 1.0f / (1.0f + exp2f(-1.44269504f * v));
}
__device__ __forceinline__ float tanhfast(float v) {
    const float e = exp2f(2.88539008f * v);
    return 1.0f - 2.0f / (e + 1.0f);
}
__device__ __forceinline__ unsigned short h2u(_Float16 h) {
    union { _Float16 h; unsigned short u; } v; v.h = h; return v.u;
}

// uncached (coherence-point) ops; caller drains vmcnt before consuming loads.
__device__ __forceinline__ f16x8 ld128_coh(const unsigned short* p) {
    f16x8 r;
    asm volatile("global_load_dwordx4 %0, %1, off sc0 sc1"
                 : "=v"(r) : "v"(p) : "memory");
    return r;
}
__device__ __forceinline__ f32x2 ld64f_coh(const float* p) {
    f32x2 r;
    asm volatile("global_load_dwordx2 %0, %1, off sc0 sc1"
                 : "=v"(r) : "v"(p) : "memory");
    return r;
}
__device__ __forceinline__ void st64f_coh(float* p, f32x2 v) {
    asm volatile("global_store_dwordx2 %0, %1, off sc0 sc1"
                 :: "v"(p), "v"(v) : "memory");
}
__device__ __forceinline__ int ld_slot(const int* slots, int i) {
    return __hip_atomic_load(&slots[i * 16], __ATOMIC_RELAXED, __HIP_MEMORY_SCOPE_AGENT);
}
__device__ __forceinline__ int packcol(int p) {
    return (((p >> 2) & 3) * H_) + ((p >> 4) << 2) + (p & 3);
}

// ---- repack: W -> packed-col-major fp16 ----
__global__ __launch_bounds__(256) void repack_w(
    const float* __restrict__ s1, const float* __restrict__ s2,
    int k1, int K, int srcld, int dopack, unsigned short* __restrict__ dst)
{
    const int p  = blockIdx.x;
    const int kk = blockIdx.y * 256 + threadIdx.x;
    if (kk >= K) return;
    const int oc = dopack ? packcol(p) : p;
    const float w = (kk < k1) ? s1[(size_t)kk * srcld + oc]
                              : s2[(size_t)(kk - k1) * srcld + oc];
    dst[(size_t)p * K + kk] = h2u((_Float16)w);
}

__global__ __launch_bounds__(256) void repack_bias(
    const float* __restrict__ bx0, const float* __restrict__ bh0,
    const float* __restrict__ bx1, const float* __restrict__ bh1,
    char* __restrict__ wsb)
{
    const int q = blockIdx.x * 256 + threadIdx.x;
    if (q >= 2 * G_) return;
    const int p  = q & (G_ - 1);
    const int oc = packcol(p);
    float* dst = (float*)(wsb + (q < G_ ? OB_B0 : OB_B1));
    dst[p] = (q < G_) ? (bx0[oc] + bh0[oc]) : (bx1[oc] + bh1[oc]);
}

// x -> fragment layout: xf[((t*16 + kw)*64 + l)*8 + j] = x[r=l&31][t][kw*16 + (l>>5)*8 + j]
__global__ __launch_bounds__(256) void repack_x(const float* __restrict__ x, char* __restrict__ wsb)
{
    unsigned short* xf = (unsigned short*)(wsb + OB_XF);
    const size_t n = (size_t)S_ * 16 * 512;
    for (size_t i = (size_t)blockIdx.x * 256 + threadIdx.x; i < n; i += (size_t)gridDim.x * 256) {
        const int j  = (int)(i & 7);
        const int l  = (int)((i >> 3) & 63);
        const int kw = (int)((i >> 9) & 15);
        const int t  = (int)(i >> 13);
        const int r  = l & 31;
        const int u  = kw * 16 + ((l >> 5) << 3) + j;
        xf[i] = h2u((_Float16)x[((size_t)r * S_ + t) * DIN + u]);
    }
}

// ---- L0 matmul body: x (cached frag) + h0[t-1] (uncached frag) ----
__device__ __forceinline__ void phase_mm_l0(
    int k0, int lane, int t, int xsplit,
    const float* __restrict__ x, const unsigned short* __restrict__ XF,
    const unsigned short* A1, const unsigned short* Wlds, f32x16& acc)
{
    const int colc = lane & 31, halfl = lane >> 5;
    f16x8 fh[6];
    #pragma unroll
    for (int s = 0; s < 6; ++s) {
        const int kf = k0 + s * 16;
        if (kf < 256) {
            if (xsplit) {
                fh[s] = *(const f16x8*)(XF + ((size_t)t * 16 + (kf >> 4)) * 512 + lane * 8);
            } else {
                const float* xp = x + ((size_t)colc * S_ + t) * DIN + kf + halfl * 8;
                #pragma unroll
                for (int j = 0; j < 8; ++j) fh[s][j] = (_Float16)xp[j];
            }
        } else {
            fh[s] = ld128_coh(A1 + ((kf - 256) >> 4) * 512 + lane * 8);
        }
    }
    asm volatile("s_waitcnt vmcnt(0)" ::: "memory");
    __builtin_amdgcn_sched_barrier(0);
    #pragma unroll
    for (int s = 0; s < 6; ++s) {
        const int k8a = ((k0 + s * 16) >> 3) + halfl;
        const f16x8 bw = *(const f16x8*)(Wlds + (k8a * 32 + colc) * 8);
        acc = MFMA(fh[s], bw, acc);
    }
}

// ---- single-source matmul body (fragment layout, coalesced) ----
__device__ __forceinline__ void phase_mm_single(
    int k0, int lane,
    const unsigned short* A, const unsigned short* Wlds, f32x16& acc)
{
    const int colc = lane & 31, halfl = lane >> 5;
    f16x8 fh[4];
    #pragma unroll
    for (int s = 0; s < 4; ++s)
        fh[s] = ld128_coh(A + ((k0 + s * 16) >> 4) * 512 + lane * 8);
    asm volatile("s_waitcnt vmcnt(0)" ::: "memory");
    __builtin_amdgcn_sched_barrier(0);
    #pragma unroll
    for (int s = 0; s < 4; ++s) {
        const int k8a = ((k0 + s * 16) >> 3) + halfl;
        const f16x8 bw = *(const f16x8*)(Wlds + (k8a * 32 + colc) * 8);
        acc = MFMA(fh[s], bw, acc);
    }
}

// ---- persistent dataflow kernel ----
// blocks [0,64): L0 ; [64,128): L1A ; [128,192): L1B ; [192,200): FC.
// All waits block-wide, wave-0 polled, register-cached (R12/R14 proven protocol).
__global__ __launch_bounds__(512, 2) void lstm_persist(
    const float* __restrict__ x, const float* __restrict__ bfc,
    float* __restrict__ out, char* __restrict__ wsb, int xsplit)
{
    extern __shared__ char smem[];
    unsigned short* Wlds = (unsigned short*)smem;
    float* Pt   = (float*)(smem + LS_PT);
    float* cstL = (float*)(smem + LS_CST);
    int* slots  = (int*)(wsb + OB_SLOT);

    const int blk = blockIdx.x, tid = threadIdx.x;
    const int wave = tid >> 6, lane = tid & 63;
    const int colc = lane & 31, halfl = lane >> 5;

    int role, bb;
    if (blk < 64)       { role = 0; bb = blk; }
    else if (blk < 128) { role = 1; bb = blk - 64; }
    else if (blk < 192) { role = 2; bb = blk - 128; }
    else                { role = 3; bb = blk - 192; }

    const int p0 = bb * 32;

    // stage this block's weight K-slice into LDS once: [k8*32 + col][8 fp16]
    {
        const unsigned short* Wg;
        int wstride, rowoff, kcnt2;
        if (role == 0)      { Wg = (const unsigned short*)(wsb + OB_W0); wstride = 768;  rowoff = 0;   kcnt2 = 768; }
        else if (role == 1) { Wg = (const unsigned short*)(wsb + OB_W1); wstride = 1024; rowoff = 0;   kcnt2 = 512; }
        else if (role == 2) { Wg = (const unsigned short*)(wsb + OB_W1); wstride = 1024; rowoff = 512; kcnt2 = 512; }
        else                { Wg = (const unsigned short*)(wsb + OB_WF); wstride = 512;  rowoff = 0;   kcnt2 = 512; }
        for (int idx = tid; idx < (kcnt2 >> 3) * 32; idx += 512) {
            const int k8 = idx >> 5, cl = idx & 31;
            *(f16x8*)(Wlds + idx * 8) =
                *(const f16x8*)(Wg + ((size_t)(p0 + cl) * wstride + rowoff + k8 * 8));
        }
    }
    for (int i = tid; i < 256; i += 512) cstL[i] = 0.f;
    __syncthreads();

    unsigned short* H0H = (unsigned short*)(wsb + OB_H0H);
    unsigned short* H1H = (unsigned short*)(wsb + OB_H1H);
    float* PART = (float*)(wsb + OB_PART);
    const unsigned short* XF = (const unsigned short*)(wsb + OB_XF);
    const float* Bp = (const float*)(wsb + (role == 2 ? OB_B1 : OB_B0));

    const int kcnt = (role == 0) ? 768 : 512;
    const int k0 = wave * (kcnt >> 3);
    int sA = 0, sB = 0, sC = 0;   // register-cached monotone progress

    for (int t = 0; t < T_; ++t) {
        // ---- block-wide dataflow wait (wave 0 polls; R12 mechanics) ----
        if (tid < 64) {
            if (role == 0) {                 // L0: all L0 >= t ; all L1A >= t-3
                const int tA = t, tB = t - 3;
                for (;;) {
                    bool ok = true;
                    if (sA < tA) sA = ld_slot(slots, lane);          // L0 0..63
                    ok = ok && (sA >= tA);
                    if (sB < tB) sB = ld_slot(slots, 64 + lane);     // L1A 64..127
                    ok = ok && (sB >= tB);
                    if (__all(ok)) break;
                    __builtin_amdgcn_s_sleep(1);
                }
            } else if (role == 1) {          // L1A: all L0 >= t+1 ; pair L1B >= t-3
                const int tA = t + 1, tB = t - 3;
                for (;;) {
                    bool ok = true;
                    if (sA < tA) sA = ld_slot(slots, lane);          // L0 0..63
                    ok = ok && (sA >= tA);
                    if (lane == 0) {
                        if (sB < tB) sB = ld_slot(slots, 128 + bb);  // pair L1B
                        ok = ok && (sB >= tB);
                    }
                    if (__all(ok)) break;
                    __builtin_amdgcn_s_sleep(1);
                }
            } else if (role == 2) {          // L1B: all L1B >= t ; pair L1A >= t+1 ; FC >= t-3
                const int tA = t, tB = t + 1, tC = t - 3;
                for (;;) {
                    bool ok = true;
                    if (sA < tA) sA = ld_slot(slots, 128 + lane);    // L1B 128..191
                    ok = ok && (sA >= tA);
                    if (lane == 0) {
                        if (sB < tB) sB = ld_slot(slots, 64 + bb);   // pair L1A
                        ok = ok && (sB >= tB);
                    }
                    if (lane < 8) {
                        if (sC < tC) sC = ld_slot(slots, 192 + lane);// FC 192..199
                        ok = ok && (sC >= tC);
                    }
                    if (__all(ok)) break;
                    __builtin_amdgcn_s_sleep(1);
                }
            } else {                         // FC: all L1B >= t+1
                const int tA = t + 1;
                for (;;) {
                    if (sA < tA) sA = ld_slot(slots, 128 + lane);
                    if (__all(sA >= tA)) break;
                    __builtin_amdgcn_s_sleep(1);
                }
            }
        }
        __syncthreads();

        const int pw = t & 3, pr = (t + 3) & 3;

        // L1B: pick up the paired L1A partial (uncached, drained in phase_mm)
        f32x2 preg = {0.f, 0.f};
        if (role == 2)
            preg = ld64f_coh(PART + ((size_t)(pw * 64 + bb) << 10) + tid * 2);

        f32x16 acc;
        #pragma unroll
        for (int i = 0; i < 16; ++i) acc[i] = 0.f;

        if (role == 0)
            phase_mm_l0(k0, lane, t, xsplit, x, XF, H0H + pr * 16384, Wlds, acc);
        else if (role == 1)
            phase_mm_single(k0, lane, H0H + pw * 16384, Wlds, acc);
        else if (role == 2)
            phase_mm_single(k0, lane, H1H + pr * 16384, Wlds, acc);
        else
            phase_mm_single(k0, lane, H1H + pw * 16384, Wlds, acc);

        // cross-wave K-reduce: waves 4-7 store, waves 0-3 accumulate
        if (wave >= 4) {
            #pragma unroll
            for (int rg = 0; rg < 16; ++rg) {
                const int row = (rg & 3) + 8 * (rg >> 2) + 4 * halfl;
                Pt[(wave - 4) * 1024 + row * 32 + colc] = acc[rg];
            }
        }
        __syncthreads();
        if (wave < 4) {
            #pragma unroll
            for (int rg = 0; rg < 16; ++rg) {
                const int row = (rg & 3) + 8 * (rg >> 2) + 4 * halfl;
                Pt[wave * 1024 + row * 32 + colc] += acc[rg];
            }
        }
        __syncthreads();

        if (role == 1) {
            // L1A: write partial gate sums (no bias) to the pair's mailbox
            f32x2 pv;
            #pragma unroll
            for (int ii = 0; ii < 2; ++ii) {
                const int idx = tid * 2 + ii;
                pv[ii] = Pt[idx] + Pt[1024 + idx] + Pt[2048 + idx] + Pt[3072 + idx];
            }
            st64f_coh(PART + ((size_t)(pw * 64 + bb) << 10) + tid * 2, pv);
        } else if (role == 3) {
            #pragma unroll
            for (int ii = 0; ii < 2; ++ii) {
                const int idx = tid * 2 + ii;
                const int r = idx >> 5, c = idx & 31;
                const float v = Pt[idx] + Pt[1024 + idx] + Pt[2048 + idx] + Pt[3072 + idx]
                              + bfc[p0 + c];
                out[((size_t)r * S_ + t) * DOUT + p0 + c] = v;
            }
        } else {
            // L0 / L1B: finish gates
            #pragma unroll
            for (int ii = 0; ii < 2; ++ii) {
                const int idx = tid * 2 + ii;
                float v = Pt[idx] + Pt[1024 + idx] + Pt[2048 + idx] + Pt[3072 + idx]
                        + Bp[p0 + (idx & 31)];
                if (role == 2) v += preg[ii];
                Pt[idx] = v;
            }
            __syncthreads();
            if (tid < 128) {
                const int r = tid >> 2, u2 = (tid & 3) * 2;      // units u2, u2+1
                const int cb = ((u2 >> 2) << 4) + (u2 & 3);
                unsigned short uh[2];
                #pragma unroll
                for (int uu = 0; uu < 2; ++uu) {
                    const float fg = Pt[r * 32 + cb + uu + 0];
                    const float ig = Pt[r * 32 + cb + uu + 4];
                    const float gg = Pt[r * 32 + cb + uu + 8];
                    const float og = Pt[r * 32 + cb + uu + 12];
                    const float cv = cstL[r * 8 + u2 + uu];
                    const float cn = sigf(fg) * cv + sigf(ig) * tanhfast(gg);
                    const float hn = sigf(og) * tanhfast(cn);
                    cstL[r * 8 + u2 + uu] = cn;
                    uh[uu] = h2u((_Float16)hn);
                }
                const unsigned wv = (unsigned)uh[0] | ((unsigned)uh[1] << 16);
                // FRAGMENT layout: unit bb*8+u2 -> kw=bb>>1, lane=r+32*(bb&1), j=u2
                const int off = pw * 16384 + (bb >> 1) * 512
                              + (r + ((bb & 1) << 5)) * 8 + u2;     // even element
                unsigned short* DH = (role == 0) ? H0H : H1H;
                __hip_atomic_store((unsigned*)(DH + off), wv,
                                   __ATOMIC_RELAXED, __HIP_MEMORY_SCOPE_AGENT);
            }
        }

        // ---- publish (syncthreads drains each wave's stores first) ----
        __syncthreads();
        if (tid == 0)
            __hip_atomic_store(&slots[blk * 16], t + 1,
                               __ATOMIC_RELAXED, __HIP_MEMORY_SCOPE_AGENT);
    }
}

extern "C" void kernel_launch(void* const* d_in, const int* in_sizes, int n_in,
                              void* d_out, int out_size, void* d_ws, size_t ws_size,
                              hipStream_t stream)
{
    const float* x   = (const float*)d_in[0];
    const float* Wx0 = (const float*)d_in[1];
    const float* bx0 = (const float*)d_in[2];
    const float* Wh0 = (const float*)d_in[3];
    const float* bh0 = (const float*)d_in[4];
    const float* Wx1 = (const float*)d_in[5];
    const float* bx1 = (const float*)d_in[6];
    const float* Wh1 = (const float*)d_in[7];
    const float* bh1 = (const float*)d_in[8];
    const float* Wfc = (const float*)d_in[9];
    const float* bfc = (const float*)d_in[10];
    float* out = (float*)d_out;
    char*  wsb = (char*)d_ws;

    const int xsplit = (ws_size >= OB_XEND) ? 1 : 0;

    hipMemsetAsync(d_ws, 0, OB_STATE_END, stream);

    repack_w<<<dim3(G_, 3), 256, 0, stream>>>(Wx0, Wh0, 256, 768, G_, 1,
        (unsigned short*)(wsb + OB_W0));
    repack_w<<<dim3(G_, 4), 256, 0, stream>>>(Wx1, Wh1, 512, 1024, G_, 1,
        (unsigned short*)(wsb + OB_W1));
    repack_w<<<dim3(DOUT, 2), 256, 0, stream>>>(Wfc, Wfc, 512, 512, DOUT, 0,
        (unsigned short*)(wsb + OB_WF));
    repack_bias<<<16, 256, 0, stream>>>(bx0, bh0, bx1, bh1, wsb);
    if (xsplit) repack_x<<<2048, 256, 0, stream>>>(x, wsb);

    hipFuncSetAttribute((const void*)lstm_persist,
                        hipFuncAttributeMaxDynamicSharedMemorySize, LS_TOTAL);
    lstm_persist<<<NBLK, 512, LS_TOTAL, stream>>>(x, bfc, out, wsb, xsplit);
}

// Round 19
// 9217.750 us; speedup vs baseline: 1.0114x; 1.0114x over previous
//
#include <hip/hip_runtime.h>
#include <math.h>

#define B_    32
#define S_    2048
#define DIN   256
#define H_    512
#define G_    2048
#define DOUT  256
#define T_    2048
#define NBLK  200

typedef __attribute__((ext_vector_type(8))) _Float16 f16x8;
typedef __attribute__((ext_vector_type(16))) float f32x16;
typedef __attribute__((ext_vector_type(2))) float f32x2;

#define MFMA(a,b,c) __builtin_amdgcn_mfma_f32_32x32x16_f16((a),(b),(c),0,0,0)

// ---- ws byte offsets ----
#define OB_SLOT      0u          // 200 progress slots (int), 64B stride
#define OB_H0H       16384u      // fp16 [4][32][512] ring (32 KB/slot)
#define OB_H1H       147456u
#define OB_PART      278528u     // f32 [4][64][1024] partial-gate ring (1 MB)
#define OB_STATE_END 1327104u
#define OB_B0        1327104u    // fp32 [2048] combined bias (packed cols)
#define OB_B1        1335296u
#define OB_WF        1343488u    // fp16 [256][512]   Wfc^T
#define OB_W0        1605632u    // fp16 [2048][768]  packed-col-major
#define OB_W1        4751360u    // fp16 [2048][1024]
#define OB_END       8945664u
#define OB_XH        8945664u    // fp16 [32][2048][256]
#define OB_XEND      42500096u

// ---- dynamic LDS ----
#define LS_PT    49152           // W: [0,49152) ; Pt: float[4][32][32]
#define LS_CST   65536           // float[256]
#define LS_TOTAL 66560

__device__ __forceinline__ float sigf(float v) {
    return 1.0f / (1.0f + exp2f(-1.44269504f * v));
}
__device__ __forceinline__ float tanhfast(float v) {
    const float e = exp2f(2.88539008f * v);
    return 1.0f - 2.0f / (e + 1.0f);
}
__device__ __forceinline__ unsigned short h2u(_Float16 h) {
    union { _Float16 h; unsigned short u; } v; v.h = h; return v.u;
}

// uncached (coherence-point) ops; caller drains vmcnt before consuming loads.
__device__ __forceinline__ f16x8 ld128_coh(const unsigned short* p) {
    f16x8 r;
    asm volatile("global_load_dwordx4 %0, %1, off sc0 sc1"
                 : "=v"(r) : "v"(p) : "memory");
    return r;
}
__device__ __forceinline__ f32x2 ld64f_coh(const float* p) {
    f32x2 r;
    asm volatile("global_load_dwordx2 %0, %1, off sc0 sc1"
                 : "=v"(r) : "v"(p) : "memory");
    return r;
}
__device__ __forceinline__ void st64f_coh(float* p, f32x2 v) {
    asm volatile("global_store_dwordx2 %0, %1, off sc0 sc1"
                 :: "v"(p), "v"(v) : "memory");
}
__device__ __forceinline__ int ld_slot(const int* slots, int i) {
    return __hip_atomic_load(&slots[i * 16], __ATOMIC_RELAXED, __HIP_MEMORY_SCOPE_AGENT);
}
__device__ __forceinline__ int packcol(int p) {
    return (((p >> 2) & 3) * H_) + ((p >> 4) << 2) + (p & 3);
}

// ---- repack: W -> packed-col-major fp16 ----
__global__ __launch_bounds__(256) void repack_w(
    const float* __restrict__ s1, const float* __restrict__ s2,
    int k1, int K, int srcld, int dopack, unsigned short* __restrict__ dst)
{
    const int p  = blockIdx.x;
    const int kk = blockIdx.y * 256 + threadIdx.x;
    if (kk >= K) return;
    const int oc = dopack ? packcol(p) : p;
    const float w = (kk < k1) ? s1[(size_t)kk * srcld + oc]
                              : s2[(size_t)(kk - k1) * srcld + oc];
    dst[(size_t)p * K + kk] = h2u((_Float16)w);
}

__global__ __launch_bounds__(256) void repack_bias(
    const float* __restrict__ bx0, const float* __restrict__ bh0,
    const float* __restrict__ bx1, const float* __restrict__ bh1,
    char* __restrict__ wsb)
{
    const int q = blockIdx.x * 256 + threadIdx.x;
    if (q >= 2 * G_) return;
    const int p  = q & (G_ - 1);
    const int oc = packcol(p);
    float* dst = (float*)(wsb + (q < G_ ? OB_B0 : OB_B1));
    dst[p] = (q < G_) ? (bx0[oc] + bh0[oc]) : (bx1[oc] + bh1[oc]);
}

__global__ __launch_bounds__(256) void repack_x(const float* __restrict__ x, char* __restrict__ wsb)
{
    unsigned short* xh = (unsigned short*)(wsb + OB_XH);
    const size_t n = (size_t)B_ * S_ * DIN;
    for (size_t i = (size_t)blockIdx.x * 256 + threadIdx.x; i < n; i += (size_t)gridDim.x * 256)
        xh[i] = h2u((_Float16)x[i]);
}

// ---- L0 matmul body: x (cached) + h0[t-1] (uncached), batch, drain, MFMA ----
__device__ __forceinline__ void phase_mm_l0(
    int k0, int colc, int halfl, int t, int xsplit,
    const float* __restrict__ x, const unsigned short* __restrict__ XH,
    const unsigned short* A1, const unsigned short* Wlds, f32x16& acc)
{
    f16x8 fh[6];
    #pragma unroll
    for (int s = 0; s < 6; ++s) {
        const int kf = k0 + s * 16;
        if (kf < 256) {
            const size_t o = ((size_t)colc * S_ + t) * DIN + kf + halfl * 8;
            if (xsplit) {
                fh[s] = *(const f16x8*)(XH + o);
            } else {
                const float* xp = x + o;
                #pragma unroll
                for (int j = 0; j < 8; ++j) fh[s][j] = (_Float16)xp[j];
            }
        } else {
            fh[s] = ld128_coh(A1 + colc * 512 + (kf - 256) + halfl * 8);
        }
    }
    asm volatile("s_waitcnt vmcnt(0)" ::: "memory");
    __builtin_amdgcn_sched_barrier(0);
    #pragma unroll
    for (int s = 0; s < 6; ++s) {
        const int k8a = ((k0 + s * 16) >> 3) + halfl;
        const f16x8 bw = *(const f16x8*)(Wlds + (k8a * 32 + colc) * 8);
        acc = MFMA(fh[s], bw, acc);
    }
}

// ---- single-source matmul body (L1A: h0[t], L1B: h1[t-1], FC: h1[t]) ----
__device__ __forceinline__ void phase_mm_single(
    int k0, int colc, int halfl,
    const unsigned short* A, const unsigned short* Wlds, f32x16& acc)
{
    f16x8 fh[4];
    #pragma unroll
    for (int s = 0; s < 4; ++s)
        fh[s] = ld128_coh(A + colc * 512 + (k0 + s * 16) + halfl * 8);
    asm volatile("s_waitcnt vmcnt(0)" ::: "memory");
    __builtin_amdgcn_sched_barrier(0);
    #pragma unroll
    for (int s = 0; s < 4; ++s) {
        const int k8a = ((k0 + s * 16) >> 3) + halfl;
        const f16x8 bw = *(const f16x8*)(Wlds + (k8a * 32 + colc) * 8);
        acc = MFMA(fh[s], bw, acc);
    }
}

// ---- persistent dataflow kernel ----
// blocks [0,64): L0 ; [64,128): L1A (h0-half of layer1) ;
//        [128,192): L1B (h1-half + gates) ; [192,200): FC.
// slots[blk] = timesteps completed by block blk (monotone).
// All waits are block-wide, wave-0 polled, register-cached (R12 protocol).
__global__ __launch_bounds__(512, 2) void lstm_persist(
    const float* __restrict__ x, const float* __restrict__ bfc,
    float* __restrict__ out, char* __restrict__ wsb, int xsplit)
{
    extern __shared__ char smem[];
    unsigned short* Wlds = (unsigned short*)smem;
    float* Pt   = (float*)(smem + LS_PT);
    float* cstL = (float*)(smem + LS_CST);
    int* slots  = (int*)(wsb + OB_SLOT);

    const int blk = blockIdx.x, tid = threadIdx.x;
    const int wave = tid >> 6, lane = tid & 63;
    const int colc = lane & 31, halfl = lane >> 5;

    int role, bb;
    if (blk < 64)       { role = 0; bb = blk; }
    else if (blk < 128) { role = 1; bb = blk - 64; }
    else if (blk < 192) { role = 2; bb = blk - 128; }
    else                { role = 3; bb = blk - 192; }

    const int p0 = bb * 32;

    // stage this block's weight K-slice into LDS once: [k8*32 + col][8 fp16]
    {
        const unsigned short* Wg;
        int wstride, rowoff, kcnt;
        if (role == 0)      { Wg = (const unsigned short*)(wsb + OB_W0); wstride = 768;  rowoff = 0;   kcnt = 768; }
        else if (role == 1) { Wg = (const unsigned short*)(wsb + OB_W1); wstride = 1024; rowoff = 0;   kcnt = 512; }
        else if (role == 2) { Wg = (const unsigned short*)(wsb + OB_W1); wstride = 1024; rowoff = 512; kcnt = 512; }
        else                { Wg = (const unsigned short*)(wsb + OB_WF); wstride = 512;  rowoff = 0;   kcnt = 512; }
        for (int idx = tid; idx < (kcnt >> 3) * 32; idx += 512) {
            const int k8 = idx >> 5, cl = idx & 31;
            *(f16x8*)(Wlds + idx * 8) =
                *(const f16x8*)(Wg + ((size_t)(p0 + cl) * wstride + rowoff + k8 * 8));
        }
    }
    for (int i = tid; i < 256; i += 512) cstL[i] = 0.f;
    __syncthreads();

    unsigned short* H0H = (unsigned short*)(wsb + OB_H0H);
    unsigned short* H1H = (unsigned short*)(wsb + OB_H1H);
    float* PART = (float*)(wsb + OB_PART);
    const unsigned short* XH = (const unsigned short*)(wsb + OB_XH);
    const float* Bp = (const float*)(wsb + (role == 2 ? OB_B1 : OB_B0));

    const int kcnt = (role == 0) ? 768 : 512;
    const int k0 = wave * (kcnt >> 3);
    int sA = 0, sB = 0, sC = 0;   // register-cached monotone progress

    for (int t = 0; t < T_; ++t) {
        // ---- block-wide dataflow wait (wave 0 polls; R12 mechanics) ----
        if (tid < 64) {
            if (role == 0) {                 // L0: all L0 >= t ; all L1A >= t-3
                const int tA = t, tB = t - 3;
                for (;;) {
                    bool ok = true;
                    if (sA < tA) sA = ld_slot(slots, lane);          // L0 0..63
                    ok = ok && (sA >= tA);
                    if (sB < tB) sB = ld_slot(slots, 64 + lane);     // L1A 64..127
                    ok = ok && (sB >= tB);
                    if (__all(ok)) break;
                    __builtin_amdgcn_s_sleep(1);
                }
            } else if (role == 1) {          // L1A: all L0 >= t+1 ; pair L1B >= t-3
                const int tA = t + 1, tB = t - 3;
                for (;;) {
                    bool ok = true;
                    if (sA < tA) sA = ld_slot(slots, lane);          // L0 0..63
                    ok = ok && (sA >= tA);
                    if (lane == 0) {
                        if (sB < tB) sB = ld_slot(slots, 128 + bb);  // pair L1B
                        ok = ok && (sB >= tB);
                    }
                    if (__all(ok)) break;
                    __builtin_amdgcn_s_sleep(1);
                }
            } else if (role == 2) {          // L1B: all L1B >= t ; pair L1A >= t+1 ; FC >= t-3
                const int tA = t, tB = t + 1, tC = t - 3;
                for (;;) {
                    bool ok = true;
                    if (sA < tA) sA = ld_slot(slots, 128 + lane);    // L1B 128..191
                    ok = ok && (sA >= tA);
                    if (lane == 0) {
                        if (sB < tB) sB = ld_slot(slots, 64 + bb);   // pair L1A
                        ok = ok && (sB >= tB);
                    }
                    if (lane < 8) {
                        if (sC < tC) sC = ld_slot(slots, 192 + lane);// FC 192..199
                        ok = ok && (sC >= tC);
                    }
                    if (__all(ok)) break;
                    __builtin_amdgcn_s_sleep(1);
                }
            } else {                         // FC: all L1B >= t+1
                const int tA = t + 1;
                for (;;) {
                    if (sA < tA) sA = ld_slot(slots, 128 + lane);
                    if (__all(sA >= tA)) break;
                    __builtin_amdgcn_s_sleep(1);
                }
            }
        }
        __syncthreads();

        const int pw = t & 3, pr = (t + 3) & 3;

        // L1B: pick up the paired L1A partial (uncached, drained in phase_mm)
        f32x2 preg = {0.f, 0.f};
        if (role == 2)
            preg = ld64f_coh(PART + ((size_t)(pw * 64 + bb) << 10) + tid * 2);

        f32x16 acc;
        #pragma unroll
        for (int i = 0; i < 16; ++i) acc[i] = 0.f;

        if (role == 0)
            phase_mm_l0(k0, colc, halfl, t, xsplit, x, XH, H0H + pr * 16384, Wlds, acc);
        else if (role == 1)
            phase_mm_single(k0, colc, halfl, H0H + pw * 16384, Wlds, acc);
        else if (role == 2)
            phase_mm_single(k0, colc, halfl, H1H + pr * 16384, Wlds, acc);
        else
            phase_mm_single(k0, colc, halfl, H1H + pw * 16384, Wlds, acc);

        // cross-wave K-reduce: waves 4-7 store, waves 0-3 accumulate
        if (wave >= 4) {
            #pragma unroll
            for (int rg = 0; rg < 16; ++rg) {
                const int row = (rg & 3) + 8 * (rg >> 2) + 4 * halfl;
                Pt[(wave - 4) * 1024 + row * 32 + colc] = acc[rg];
            }
        }
        __syncthreads();
        if (wave < 4) {
            #pragma unroll
            for (int rg = 0; rg < 16; ++rg) {
                const int row = (rg & 3) + 8 * (rg >> 2) + 4 * halfl;
                Pt[wave * 1024 + row * 32 + colc] += acc[rg];
            }
        }
        __syncthreads();

        if (role == 1) {
            // L1A: write partial gate sums (no bias) to the pair's mailbox
            f32x2 pv;
            #pragma unroll
            for (int ii = 0; ii < 2; ++ii) {
                const int idx = tid * 2 + ii;
                pv[ii] = Pt[idx] + Pt[1024 + idx] + Pt[2048 + idx] + Pt[3072 + idx];
            }
            st64f_coh(PART + ((size_t)(pw * 64 + bb) << 10) + tid * 2, pv);
        } else if (role == 3) {
            #pragma unroll
            for (int ii = 0; ii < 2; ++ii) {
                const int idx = tid * 2 + ii;
                const int r = idx >> 5, c = idx & 31;
                const float v = Pt[idx] + Pt[1024 + idx] + Pt[2048 + idx] + Pt[3072 + idx]
                              + bfc[p0 + c];
                out[((size_t)r * S_ + t) * DOUT + p0 + c] = v;
            }
        } else {
            // L0 / L1B: finish gates
            #pragma unroll
            for (int ii = 0; ii < 2; ++ii) {
                const int idx = tid * 2 + ii;
                float v = Pt[idx] + Pt[1024 + idx] + Pt[2048 + idx] + Pt[3072 + idx]
                        + Bp[p0 + (idx & 31)];
                if (role == 2) v += preg[ii];
                Pt[idx] = v;
            }
            __syncthreads();
            if (tid < 128) {
                const int r = tid >> 2, u2 = (tid & 3) * 2;      // units u2, u2+1
                const int cb = ((u2 >> 2) << 4) + (u2 & 3);
                unsigned short uh[2];
                #pragma unroll
                for (int uu = 0; uu < 2; ++uu) {
                    const float fg = Pt[r * 32 + cb + uu + 0];
                    const float ig = Pt[r * 32 + cb + uu + 4];
                    const float gg = Pt[r * 32 + cb + uu + 8];
                    const float og = Pt[r * 32 + cb + uu + 12];
                    const float cv = cstL[r * 8 + u2 + uu];
                    const float cn = sigf(fg) * cv + sigf(ig) * tanhfast(gg);
                    const float hn = sigf(og) * tanhfast(cn);
                    cstL[r * 8 + u2 + uu] = cn;
                    uh[uu] = h2u((_Float16)hn);
                }
                const unsigned wv = (unsigned)uh[0] | ((unsigned)uh[1] << 16);
                const int off = pw * 16384 + r * 512 + bb * 8 + u2;   // even element
                unsigned short* DH = (role == 0) ? H0H : H1H;
                __hip_atomic_store((unsigned*)(DH + off), wv,
                                   __ATOMIC_RELAXED, __HIP_MEMORY_SCOPE_AGENT);
            }
        }

        // ---- publish (syncthreads drains each wave's stores first) ----
        __syncthreads();
        if (tid == 0)
            __hip_atomic_store(&slots[blk * 16], t + 1,
                               __ATOMIC_RELAXED, __HIP_MEMORY_SCOPE_AGENT);
    }
}

extern "C" void kernel_launch(void* const* d_in, const int* in_sizes, int n_in,
                              void* d_out, int out_size, void* d_ws, size_t ws_size,
                              hipStream_t stream)
{
    const float* x   = (const float*)d_in[0];
    const float* Wx0 = (const float*)d_in[1];
    const float* bx0 = (const float*)d_in[2];
    const float* Wh0 = (const float*)d_in[3];
    const float* bh0 = (const float*)d_in[4];
    const float* Wx1 = (const float*)d_in[5];
    const float* bx1 = (const float*)d_in[6];
    const float* Wh1 = (const float*)d_in[7];
    const float* bh1 = (const float*)d_in[8];
    const float* Wfc = (const float*)d_in[9];
    const float* bfc = (const float*)d_in[10];
    float* out = (float*)d_out;
    char*  wsb = (char*)d_ws;

    const int xsplit = (ws_size >= OB_XEND) ? 1 : 0;

    hipMemsetAsync(d_ws, 0, OB_STATE_END, stream);

    repack_w<<<dim3(G_, 3), 256, 0, stream>>>(Wx0, Wh0, 256, 768, G_, 1,
        (unsigned short*)(wsb + OB_W0));
    repack_w<<<dim3(G_, 4), 256, 0, stream>>>(Wx1, Wh1, 512, 1024, G_, 1,
        (unsigned short*)(wsb + OB_W1));
    repack_w<<<dim3(DOUT, 2), 256, 0, stream>>>(Wfc, Wfc, 512, 512, DOUT, 0,
        (unsigned short*)(wsb + OB_WF));
    repack_bias<<<16, 256, 0, stream>>>(bx0, bh0, bx1, bh1, wsb);
    if (xsplit) repack_x<<<2048, 256, 0, stream>>>(x, wsb);

    hipFuncSetAttribute((const void*)lstm_persist,
                        hipFuncAttributeMaxDynamicSharedMemorySize, LS_TOTAL);
    lstm_persist<<<NBLK, 512, LS_TOTAL, stream>>>(x, bfc, out, wsb, xsplit);
}